// Round 3
// baseline (359.824 us; speedup 1.0000x reference)
//
#include <hip/hip_runtime.h>
#include <stdint.h>
#include <stddef.h>

// SplitConv4Pim forward on MI355X — 8-phase-style pipelined implicit-GEMM conv.
// ws layout: [wq bf16: 4,718,592 B][xt bf16: 27,557,888 B]

typedef __bf16 bf16_t;
typedef __bf16 bf16x8 __attribute__((ext_vector_type(8)));
typedef float  f32x4  __attribute__((ext_vector_type(4)));

#define WS_XT_OFF 4718592

__device__ __forceinline__ void gload16(const void* g, void* l) {
  __builtin_amdgcn_global_load_lds(
      (const __attribute__((address_space(1))) uint32_t*)g,
      (__attribute__((address_space(3))) uint32_t*)l, 16, 0, 0);
}

// ---- P1: weight quantization: w[o][ic][ky][kx] f32 -> wq[o][kpos][ic] bf16 ----
__global__ void quant_w_k(const float* __restrict__ w,
                          const float* __restrict__ wsc,
                          bf16_t* __restrict__ wqo) {
  int idx = blockIdx.x * 256 + threadIdx.x;
  int ic   = idx & 255;
  int t2   = idx >> 8;
  int kpos = t2 % 9;
  int o    = t2 / 9;
  float s  = wsc[ic >> 5];
  float wv = w[o * 2304 + ic * 9 + kpos];
  float wi = rintf(wv / s);
  wi = fminf(127.f, fmaxf(-128.f, wi));
  int u = (int)wi + 128;
  int q = (u >> 6) & 3;
  float wsplit = (float)(q * 64 - 128);
  wqo[idx] = (bf16_t)(wsplit * s);
}

// ---- P2: x NCHW f32 -> padded NHWC bf16 xt[16][58][58][256] ----
__global__ void pad_x_k(const float* __restrict__ x, bf16_t* __restrict__ xt) {
  __shared__ bf16_t tile[56 * 258];
  int b  = blockIdx.x / 58;
  int yo = blockIdx.x % 58;
  int t  = threadIdx.x;
  bf16_t* dst = xt + (size_t)(b * 58 + yo) * 58 * 256;
  if (yo == 0 || yo == 57) {
    for (int i = 0; i < 58; ++i) dst[i * 256 + t] = (bf16_t)0.0f;
    return;
  }
  const float* src = x + (size_t)b * 256 * 3136 + (yo - 1) * 56;
  for (int i = 0; i < 56 * 256; i += 256) {
    int lin = i + t;
    int c  = lin / 56;
    int xx = lin - c * 56;
    tile[xx * 258 + c] = (bf16_t)src[c * 3136 + xx];
  }
  __syncthreads();
  for (int xo = 0; xo < 58; ++xo) {
    bf16_t v = (bf16_t)0.0f;
    if (xo >= 1 && xo <= 56) v = tile[(xo - 1) * 258 + t];
    dst[xo * 256 + t] = v;
  }
}

// ---- main: 256m x 128oc tile, BK=64, triple-buffer LDS, counted-vmcnt pipeline ----
// grid 392 = 196 m-tiles x 2 oc-tiles, 512 threads (8 waves: 2 oc-halves x 4 m-quarters,
// per-wave 64oc x 64m). K-tiles: 144 = 4 groups x 36 (9 taps x 4 ic64-blocks).
__global__ __launch_bounds__(512, 2)
void conv_q_k(const bf16_t* __restrict__ xt, const bf16_t* __restrict__ wq,
              const float* __restrict__ ps, float* __restrict__ out) {
  __shared__ alignas(16) bf16_t Ab[3][128 * 64];   // 48 KB: weights [128 oc][64 k]
  __shared__ alignas(16) bf16_t Bb[3][256 * 64];   // 96 KB: x       [256 m ][64 k]

  const int tid  = threadIdx.x;
  const int lane = tid & 63;
  const int wave = tid >> 6;

  // T1 XCD swizzle (392 = 8 x 49, bijective), n-major: XCD 0-3 -> oc half 0, 4-7 -> half 1.
  const int bid  = blockIdx.x;
  const int s    = (bid & 7) * 49 + (bid >> 3);
  const int nsel = (s >= 196) ? 1 : 0;
  const int n0   = nsel << 7;
  const int m0   = (s - nsel * 196) << 8;

  // ---- staging map: thread t stages 16B chunk; row = tid>>3 (+64q), phys slot = tid&7.
  // T2 swizzle (both-sides XOR, rule #21): source slot = phys ^ (row&7); read XORs same.
  const int srow = tid >> 3;
  const int sOff = (((tid & 7) ^ (srow & 7)) << 3);    // source elem offset of 16B chunk
  int rbq[4];
#pragma unroll
  for (int q = 0; q < 4; ++q) {
    int gm = m0 + srow + (q << 6);
    int b = gm / 3136, rem = gm - b * 3136;
    int oy = rem / 56, ox = rem - oy * 56;
    rbq[q] = (((b * 58 + oy) * 58 + ox) << 8) + sOff;
  }
  const int wrow0 = (n0 + srow) * 2304 + sOff;         // weight rows (q=0 / q=1)
  const int wrow1 = wrow0 + 64 * 2304;
  char* const ldA = (char*)&Ab[0][0] + (tid << 4);
  char* const ldB = (char*)&Bb[0][0] + (tid << 4);

  // ---- compute map: per-wave 64oc x 64m; frag (io,jm) of 16x16, K sub ks=0/1 ----
  const int wr = wave >> 2, wc = wave & 3;
  const int rr = lane & 15, hi = lane >> 4;
  const int aRow = (wr * 64 + rr) * 128;               // byte offset of A row
  const int bRow = (wc * 64 + rr) * 128;               // byte offset of B row
  const int sl0 = (((0) | hi) ^ (rr & 7)) << 4;        // swizzled 16B slot, ks=0
  const int sl1 = (((4) | hi) ^ (rr & 7)) << 4;        // swizzled 16B slot, ks=1

  f32x4 acc[4][4], oacc[4][4];                          // [io][jm]
#pragma unroll
  for (int i = 0; i < 4; ++i)
#pragma unroll
    for (int j = 0; j < 4; ++j)
#pragma unroll
      for (int k = 0; k < 4; ++k) { acc[i][j][k] = 0.f; oacc[i][j][k] = 0.f; }

  const char* const Abase = (const char*)&Ab[0][0];
  const char* const Bbase = (const char*)&Bb[0][0];

  // kt in [0,144): g = kt/36, r = kt%36, kpos = r>>2 (tap), icb = (r&3)*64
  auto S_A = [&](int kt, int nb) {
    int g = kt / 36, r = kt - g * 36;
    int kpos = r >> 2, icb = (r & 3) << 6;
    int wof = g * 589824 + kpos * 256 + icb;
    char* la = ldA + nb * 16384;
    gload16(wq + wrow0 + wof, la);
    gload16(wq + wrow1 + wof, la + 8192);
  };
  auto S_B = [&](int kt, int nb, int half) {           // x is group-independent
    int g = kt / 36, r = kt - g * 36;
    int kpos = r >> 2, icb = (r & 3) << 6;
    int ky = kpos / 3, kx = kpos - ky * 3;
    int xof = ((ky * 58 + kx) << 8) + icb;
    char* lb = ldB + nb * 32768 + half * 16384;
    gload16(xt + rbq[half * 2]     + xof, lb);
    gload16(xt + rbq[half * 2 + 1] + xof, lb + 8192);
  };

  // ---- tile body: 2 phases x 16 MFMA, STAGE(t+2) interleaved, vmcnt(6) once ----
  auto body = [&](int t, int cur) {
    const int nb = (cur + 2 >= 3) ? (cur - 1) : (cur + 2);   // (t+2)%3
    const char* Ac = Abase + cur * 16384;
    const char* Bc = Bbase + cur * 32768;
    const bool pf = (t + 2 < 144);

    // R0: read av (all) + bv jm0,1; issue A + B-half0 of t+2
    bf16x8 av[4][2], bv01[2][2];
#pragma unroll
    for (int io = 0; io < 4; ++io) {
      av[io][0] = *(const bf16x8*)(Ac + aRow + io * 2048 + sl0);
      av[io][1] = *(const bf16x8*)(Ac + aRow + io * 2048 + sl1);
    }
#pragma unroll
    for (int jm = 0; jm < 2; ++jm) {
      bv01[jm][0] = *(const bf16x8*)(Bc + bRow + jm * 2048 + sl0);
      bv01[jm][1] = *(const bf16x8*)(Bc + bRow + jm * 2048 + sl1);
    }
    if (pf) { S_A(t + 2, nb); S_B(t + 2, nb, 0); }
    __builtin_amdgcn_s_barrier();
    asm volatile("s_waitcnt lgkmcnt(0)" ::: "memory");
    __builtin_amdgcn_sched_barrier(0);
    __builtin_amdgcn_s_setprio(1);
#pragma unroll
    for (int ks = 0; ks < 2; ++ks)
#pragma unroll
      for (int io = 0; io < 4; ++io) {
        acc[io][0] = __builtin_amdgcn_mfma_f32_16x16x32_bf16(av[io][ks], bv01[0][ks], acc[io][0], 0, 0, 0);
        acc[io][1] = __builtin_amdgcn_mfma_f32_16x16x32_bf16(av[io][ks], bv01[1][ks], acc[io][1], 0, 0, 0);
      }
    __builtin_amdgcn_s_setprio(0);
    __builtin_amdgcn_s_barrier();

    // R1: read bv jm2,3; issue B-half1 of t+2; counted vmcnt -> t+1 staged
    bf16x8 bv23[2][2];
#pragma unroll
    for (int jm = 0; jm < 2; ++jm) {
      bv23[jm][0] = *(const bf16x8*)(Bc + bRow + (jm + 2) * 2048 + sl0);
      bv23[jm][1] = *(const bf16x8*)(Bc + bRow + (jm + 2) * 2048 + sl1);
    }
    if (pf) S_B(t + 2, nb, 1);
    if (t < 142) asm volatile("s_waitcnt vmcnt(6)" ::: "memory");
    else         asm volatile("s_waitcnt vmcnt(0)" ::: "memory");
    __builtin_amdgcn_s_barrier();
    asm volatile("s_waitcnt lgkmcnt(0)" ::: "memory");
    __builtin_amdgcn_sched_barrier(0);
    __builtin_amdgcn_s_setprio(1);
#pragma unroll
    for (int ks = 0; ks < 2; ++ks)
#pragma unroll
      for (int io = 0; io < 4; ++io) {
        acc[io][2] = __builtin_amdgcn_mfma_f32_16x16x32_bf16(av[io][ks], bv23[0][ks], acc[io][2], 0, 0, 0);
        acc[io][3] = __builtin_amdgcn_mfma_f32_16x16x32_bf16(av[io][ks], bv23[1][ks], acc[io][3], 0, 0, 0);
      }
    __builtin_amdgcn_s_setprio(0);
    __builtin_amdgcn_s_barrier();

    // group boundary: quantize psum into oacc (register-only; safe after barrier)
    if ((t & 3) == 3 && (t % 36) == 35) {
      const float sp  = ps[t / 36];
      const float isp = 1.0f / sp;
#pragma unroll
      for (int io = 0; io < 4; ++io)
#pragma unroll
        for (int jm = 0; jm < 4; ++jm)
#pragma unroll
          for (int k = 0; k < 4; ++k) {
            float q = rintf(acc[io][jm][k] * isp);
            q = fminf(127.f, fmaxf(-128.f, q));
            oacc[io][jm][k] += q * sp;
            acc[io][jm][k] = 0.f;
          }
    }
  };

  // prologue: stage tiles 0 and 1, drain tile 0's loads (6 newer stay in flight)
  S_A(0, 0); S_B(0, 0, 0); S_B(0, 0, 1);
  S_A(1, 1); S_B(1, 1, 0); S_B(1, 1, 1);
  asm volatile("s_waitcnt vmcnt(6)" ::: "memory");
  __builtin_amdgcn_s_barrier();

#pragma unroll 1
  for (int tt = 0; tt < 48; ++tt) {
    body(3 * tt,     0);
    body(3 * tt + 1, 1);
    body(3 * tt + 2, 2);
  }

  // ---- store: D col=lane&15 -> m, row=(lane>>4)*4+k -> oc ----
  const int ocb = n0 + wr * 64 + (hi << 2);
#pragma unroll
  for (int jm = 0; jm < 4; ++jm) {
    int m = m0 + wc * 64 + jm * 16 + rr;
    int b = m / 3136, rem = m - b * 3136;
    int oy = rem / 56, ox = rem - oy * 56;
    int obase = b * 802816 + oy * 56 + ox;
#pragma unroll
    for (int io = 0; io < 4; ++io)
#pragma unroll
      for (int k = 0; k < 4; ++k)
        out[obase + (ocb + io * 16 + k) * 3136] = oacc[io][jm][k];
  }
}

extern "C" void kernel_launch(void* const* d_in, const int* in_sizes, int n_in,
                              void* d_out, int out_size, void* d_ws, size_t ws_size,
                              hipStream_t stream) {
  const float* x   = (const float*)d_in[0];   // [16,256,56,56]
  const float* w   = (const float*)d_in[1];   // [1024,256,3,3]
  const float* wsc = (const float*)d_in[2];   // [8]
  const float* ps  = (const float*)d_in[3];   // [4]
  float* out = (float*)d_out;                 // [16,256,56,56]
  bf16_t* wq = (bf16_t*)d_ws;
  bf16_t* xt = (bf16_t*)((char*)d_ws + WS_XT_OFF);

  quant_w_k<<<9216, 256, 0, stream>>>(w, wsc, wq);
  pad_x_k<<<16 * 58, 256, 0, stream>>>(x, xt);
  conv_q_k<<<392, 512, 0, stream>>>(xt, wq, ps, out);
}